// Round 7
// baseline (604.183 us; speedup 1.0000x reference)
//
#include <hip/hip_runtime.h>
#include <cstdint>
#include <cstddef>

// ---------------------------------------------------------------------------
// GCN 2-layer encoder.  Pipeline per launch (9 dispatches):
//   1. zero binCnt
//   2. fine_count: 782-bin histogram of dst>>7 (LDS hist, merged atomically)
//   3. bin_scan:   binStart[0..nbins] prefix + supCursor (one per 2048-node
//                  super-bin = 16 fine bins)
//   4. super_fill: partition edges into 49 super-bins via LDS tile staging
//                  (~3072-edge tile/block -> ~256 B chunky flushes)
//   5. bin_csr2:   one block per fine bin; filter-reads its super segment
//                  (L2/L3 resident) twice: count 128 nodes -> scan -> rowptr
//                  + dis (rsqrt fused), then scatter col.  Replaces the old
//                  fine_fill + node_count_dis + bin_csr trio.
//   6. gemm1 -> h1 (bf16)   7. agg1 -> out1 (bf16, relu)
//   8. gemm2 -> h2 (bf16)   9. agg2 -> d_out (fp32)
// agg computes weights on the fly: out = di*(sum_j dis[src_j]*h_j + di*h_self).
// ---------------------------------------------------------------------------

#define BIN_SHIFT 7
#define BIN_NODES 128
#define MAX_BINS 1024
#define SUP_SHIFT 11
#define NSUP_MAX 64
#define SCAP 120      // per-super LDS staging capacity (tile<=3072 -> mean ~63)
#define SF_TILE 3072  // edges per super_fill block
#define SRC_BITS 17
#define SRC_MASK ((1 << SRC_BITS) - 1)

typedef unsigned short ushort_t;

__device__ __forceinline__ float4 bfq2f4(uint2 p) {  // 4 packed bf16 -> fp32 (exact)
  float4 r;
  r.x = __uint_as_float(p.x << 16);
  r.y = __uint_as_float(p.x & 0xFFFF0000u);
  r.z = __uint_as_float(p.y << 16);
  r.w = __uint_as_float(p.y & 0xFFFF0000u);
  return r;
}
__device__ __forceinline__ unsigned f2bf(float f) {  // fp32 -> bf16 bits, RNE
  unsigned u = __float_as_uint(f);
  return (u + 0x7FFFu + ((u >> 16) & 1u)) >> 16;
}
__device__ __forceinline__ uint2 f42bfq(float4 f) {
  uint2 r;
  r.x = f2bf(f.x) | (f2bf(f.y) << 16);
  r.y = f2bf(f.z) | (f2bf(f.w) << 16);
  return r;
}

__global__ void zero_int(int* __restrict__ p, int n) {
  int i = blockIdx.x * blockDim.x + threadIdx.x;
  if (i < n) p[i] = 0;
}

// --- pass 2: fine-bin histogram ---------------------------------------------
__global__ __launch_bounds__(256) void fine_count(const int* __restrict__ dst, int E, int nbins,
                                                  int* __restrict__ binCnt) {
  __shared__ int h[MAX_BINS];
  for (int i = threadIdx.x; i < nbins; i += 256) h[i] = 0;
  __syncthreads();
  int stride = gridDim.x * 256;
  for (int e = blockIdx.x * 256 + threadIdx.x; e < E; e += stride)
    atomicAdd(&h[dst[e] >> BIN_SHIFT], 1);
  __syncthreads();
  for (int i = threadIdx.x; i < nbins; i += 256)
    if (h[i]) atomicAdd(&binCnt[i], h[i]);
}

// --- pass 3: scan fine bins -> binStart; derive super cursors ---------------
__global__ __launch_bounds__(256) void bin_scan(const int* __restrict__ binCnt, int nbins, int E,
                                                int* __restrict__ binStart,
                                                int* __restrict__ supCursor) {
  __shared__ int s[256];
  int t = threadIdx.x;
  int c[4];
  int sum = 0;
#pragma unroll
  for (int i = 0; i < 4; i++) {
    int idx = t * 4 + i;
    c[i] = (idx < nbins) ? binCnt[idx] : 0;
    sum += c[i];
  }
  int v = sum;
  s[t] = v;
  __syncthreads();
  for (int d = 1; d < 256; d <<= 1) {
    int add = (t >= d) ? s[t - d] : 0;
    __syncthreads();
    s[t] += add;
    __syncthreads();
  }
  int run = s[t] - v;  // exclusive prefix
#pragma unroll
  for (int i = 0; i < 4; i++) {
    int idx = t * 4 + i;
    if (idx < nbins) {
      binStart[idx] = run;
      if ((idx & 15) == 0) supCursor[idx >> 4] = run;  // super segment start
      run += c[i];
    }
  }
  if (t == 0) binStart[nbins] = E;
}

// --- pass 4: partition into super-bins with LDS tile staging ----------------
// One <=SF_TILE-edge tile per block; flushes land as ~256 B contiguous chunks
// per super-bin.  Rare overflow (>SCAP) spills as direct global writes.
__global__ __launch_bounds__(256) void super_fill(const int* __restrict__ src,
                                                  const int* __restrict__ dst, int E, int nsup,
                                                  int* __restrict__ supCursor,
                                                  unsigned* __restrict__ supbuf) {
  __shared__ unsigned stage[NSUP_MAX * SCAP];
  __shared__ int lcnt[NSUP_MAX], lbase[NSUP_MAX], lscan[NSUP_MAX + 1];
  int c0 = blockIdx.x * SF_TILE;
  int c1 = min(E, c0 + SF_TILE);
  if (threadIdx.x < nsup) lcnt[threadIdx.x] = 0;
  __syncthreads();
  for (int e = c0 + threadIdx.x; e < c1; e += 256) {
    int d = dst[e];
    int sb = d >> SUP_SHIFT;
    unsigned v = ((unsigned)(d & ((1 << SUP_SHIFT) - 1)) << SRC_BITS) | (unsigned)src[e];
    int idx = atomicAdd(&lcnt[sb], 1);
    if (idx < SCAP)
      stage[sb * SCAP + idx] = v;
    else {  // rare overflow: direct write
      int g = atomicAdd(&supCursor[sb], 1);
      supbuf[g] = v;
    }
  }
  __syncthreads();
  if (threadIdx.x < nsup) {
    int c = min(lcnt[threadIdx.x], SCAP);
    lcnt[threadIdx.x] = c;
    lbase[threadIdx.x] = c ? atomicAdd(&supCursor[threadIdx.x], c) : 0;
  }
  __syncthreads();
  if (threadIdx.x == 0) {  // tiny serial scan over <=64 bins
    int r = 0;
    for (int i = 0; i < nsup; i++) {
      lscan[i] = r;
      r += lcnt[i];
    }
    lscan[nsup] = r;
  }
  __syncthreads();
  int total = lscan[nsup];
  for (int j = threadIdx.x; j < total; j += 256) {
    int lo = 0, hi = nsup;  // binary search: lscan[lo] <= j < lscan[lo+1]
    while (hi - lo > 1) {
      int mid = (lo + hi) >> 1;
      if (lscan[mid] <= j)
        lo = mid;
      else
        hi = mid;
    }
    int off = j - lscan[lo];
    supbuf[lbase[lo] + off] = stage[lo * SCAP + off];
  }
}

// --- pass 5: fused count+scan+rowptr+dis+col scatter per fine bin -----------
// Block b filters its super's segment (16x read redundancy, L2/L3-resident).
__global__ __launch_bounds__(256) void bin_csr2(const unsigned* __restrict__ supbuf,
                                                const int* __restrict__ binStart, int nbins,
                                                int N, int E, int* __restrict__ rowptr,
                                                float* __restrict__ dis, int* __restrict__ col) {
  __shared__ int cur[BIN_NODES];   // counts, then cursors
  __shared__ int pref[BIN_NODES];
  int b = blockIdx.x, t = threadIdx.x;
  int sb = b >> 4, myf = b & 15;
  int nodeBase = b << BIN_SHIFT;
  int seg0 = binStart[sb << 4];
  int seg1 = binStart[min((sb + 1) << 4, nbins)];
  if (t < BIN_NODES) cur[t] = 0;
  __syncthreads();
  for (int i = seg0 + t; i < seg1; i += 256) {
    unsigned dls = supbuf[i] >> SRC_BITS;
    if ((int)(dls >> BIN_SHIFT) == myf) atomicAdd(&cur[dls & (BIN_NODES - 1)], 1);
  }
  __syncthreads();
  int c = 0;
  if (t < BIN_NODES) {
    c = cur[t];
    pref[t] = c;
  }
  __syncthreads();
  for (int d = 1; d < BIN_NODES; d <<= 1) {  // inclusive scan over 128
    int add = (t < BIN_NODES && t >= d) ? pref[t - d] : 0;
    __syncthreads();
    if (t < BIN_NODES) pref[t] += add;
    __syncthreads();
  }
  int base = binStart[b];
  if (t < BIN_NODES) {
    int node = nodeBase + t;
    if (node < N) {
      int ex = base + pref[t] - c;  // exclusive prefix + segment base
      rowptr[node] = ex;
      cur[t] = ex;
      dis[node] = rsqrtf((float)(c + 1));  // +1 self loop
    }
  }
  if (b == 0 && t == 255) rowptr[N] = E;
  __syncthreads();
  for (int i = seg0 + t; i < seg1; i += 256) {  // second pass: scatter col
    unsigned v = supbuf[i];
    unsigned dls = v >> SRC_BITS;
    if ((int)(dls >> BIN_SHIFT) == myf) {
      int slot = atomicAdd(&cur[dls & (BIN_NODES - 1)], 1);
      col[slot] = v & SRC_MASK;
    }
  }
}

// --- GEMM: Cbf16[M][64] = A[M][K] @ W[K][64], W staged in LDS ---------------
// CHUNK=64 -> 16 KB LDS -> occupancy capped by VGPR/threads (8 blocks/CU at
// VGPR=64), not LDS (round 6: 32 KB -> 4 blocks/CU -> 32% occ, VALUBusy 39%).
template <int K, bool ABF16>
__global__ __launch_bounds__(256, 4) void gemm64(const void* __restrict__ Av,
                                                 const float* __restrict__ W,
                                                 uint2* __restrict__ Cb, int M) {
  constexpr int CHUNK = (K > 64) ? 64 : K;
  __shared__ float4 wlds[CHUNK * 16];

  const int c0 = threadIdx.x & 15;
  const int rq = threadIdx.x >> 4;
  const int r0 = blockIdx.x * 64 + rq * 4;

  float4 acc[4];
#pragma unroll
  for (int i = 0; i < 4; i++) acc[i] = make_float4(0.f, 0.f, 0.f, 0.f);
  size_t aoff[4];
  bool ok[4];
#pragma unroll
  for (int i = 0; i < 4; i++) {
    int r = r0 + i;
    ok[i] = (r < M);
    aoff[i] = (size_t)(ok[i] ? r : (M - 1)) * K;
  }

  for (int kc = 0; kc < K; kc += CHUNK) {
    {
      const float4* W4 = (const float4*)W + (size_t)kc * 16;
      for (int i = threadIdx.x; i < CHUNK * 16; i += 256) wlds[i] = W4[i];
    }
    __syncthreads();

#pragma unroll 2
    for (int k = 0; k < CHUNK; k += 4) {
      float4 xv[4];
#pragma unroll
      for (int i = 0; i < 4; i++) {
        size_t idx = aoff[i] + kc + k;
        if (ABF16)
          xv[i] = bfq2f4(*(const uint2*)((const ushort_t*)Av + idx));
        else
          xv[i] = *(const float4*)((const float*)Av + idx);
      }
      float4 w0 = wlds[(k + 0) * 16 + c0];
      float4 w1 = wlds[(k + 1) * 16 + c0];
      float4 w2 = wlds[(k + 2) * 16 + c0];
      float4 w3 = wlds[(k + 3) * 16 + c0];
#pragma unroll
      for (int i = 0; i < 4; i++) {
        acc[i].x += xv[i].x * w0.x + xv[i].y * w1.x + xv[i].z * w2.x + xv[i].w * w3.x;
        acc[i].y += xv[i].x * w0.y + xv[i].y * w1.y + xv[i].z * w2.y + xv[i].w * w3.y;
        acc[i].z += xv[i].x * w0.z + xv[i].y * w1.z + xv[i].z * w2.z + xv[i].w * w3.z;
        acc[i].w += xv[i].x * w0.w + xv[i].y * w1.w + xv[i].z * w2.w + xv[i].w * w3.w;
      }
    }
    __syncthreads();
  }
#pragma unroll
  for (int i = 0; i < 4; i++)
    if (ok[i]) Cb[(size_t)(r0 + i) * 16 + c0] = f42bfq(acc[i]);
}

// --- aggregation: wave per node, 4 edges/wave, bf16 gather, on-the-fly w ----
template <bool OUTBF>
__global__ __launch_bounds__(256) void agg_kernel(
    const uint2* __restrict__ h, const int* __restrict__ rowptr, const int* __restrict__ col,
    const float* __restrict__ dis, const float* __restrict__ bias, void* __restrict__ outv,
    int N, int relu) {
  int wid = (blockIdx.x * blockDim.x + threadIdx.x) >> 6;
  if (wid >= N) return;
  int lane = threadIdx.x & 63;
  int sub = lane & 15;
  int quarter = lane >> 4;

  int start = rowptr[wid], end = rowptr[wid + 1];
  float di = dis[wid];

  float4 a0 = make_float4(0.f, 0.f, 0.f, 0.f), a1 = a0, a2 = a0, a3 = a0;
  {  // self-loop: di*h_self (quarter 0 only); final *di makes it di^2
    float4 self = bfq2f4(h[(size_t)wid * 16 + sub]);
    if (quarter == 0) {
      a0.x = di * self.x;
      a0.y = di * self.y;
      a0.z = di * self.z;
      a0.w = di * self.w;
    }
  }

  for (int base = start; base < end; base += 64) {
    int e = base + lane;
    int sj = 0;
    float wj = 0.f;
    if (e < end) {
      sj = col[e];
      wj = dis[sj];  // L2-resident 400 KB table
    }
    int cnt = end - base;
    if (cnt > 64) cnt = 64;
    int rounds = (cnt + 3) >> 2;
    int t = 0;
    for (; t + 4 <= rounds; t += 4) {
      int i0 = 4 * t + quarter;
      int s0 = __shfl(sj, i0), s1 = __shfl(sj, i0 + 4), s2 = __shfl(sj, i0 + 8),
          s3 = __shfl(sj, i0 + 12);
      float w0 = __shfl(wj, i0), w1 = __shfl(wj, i0 + 4), w2 = __shfl(wj, i0 + 8),
            w3 = __shfl(wj, i0 + 12);
      float4 g0 = bfq2f4(h[(size_t)s0 * 16 + sub]);
      float4 g1 = bfq2f4(h[(size_t)s1 * 16 + sub]);
      float4 g2 = bfq2f4(h[(size_t)s2 * 16 + sub]);
      float4 g3 = bfq2f4(h[(size_t)s3 * 16 + sub]);
      a0.x += w0 * g0.x; a0.y += w0 * g0.y; a0.z += w0 * g0.z; a0.w += w0 * g0.w;
      a1.x += w1 * g1.x; a1.y += w1 * g1.y; a1.z += w1 * g1.z; a1.w += w1 * g1.w;
      a2.x += w2 * g2.x; a2.y += w2 * g2.y; a2.z += w2 * g2.z; a2.w += w2 * g2.w;
      a3.x += w3 * g3.x; a3.y += w3 * g3.y; a3.z += w3 * g3.z; a3.w += w3 * g3.w;
    }
    for (; t < rounds; t++) {
      int i0 = 4 * t + quarter;  // tail quarters past cnt have wj==0
      int s0 = __shfl(sj, i0);
      float w0 = __shfl(wj, i0);
      float4 g0 = bfq2f4(h[(size_t)s0 * 16 + sub]);
      a0.x += w0 * g0.x; a0.y += w0 * g0.y; a0.z += w0 * g0.z; a0.w += w0 * g0.w;
    }
  }

  float sx = (a0.x + a1.x) + (a2.x + a3.x);
  float sy = (a0.y + a1.y) + (a2.y + a3.y);
  float sz = (a0.z + a1.z) + (a2.z + a3.z);
  float sw = (a0.w + a1.w) + (a2.w + a3.w);
  sx += __shfl_down(sx, 32); sy += __shfl_down(sy, 32);
  sz += __shfl_down(sz, 32); sw += __shfl_down(sw, 32);
  sx += __shfl_down(sx, 16); sy += __shfl_down(sy, 16);
  sz += __shfl_down(sz, 16); sw += __shfl_down(sw, 16);
  if (quarter == 0) {
    float4 bv = ((const float4*)bias)[sub];
    float4 o = make_float4(di * sx + bv.x, di * sy + bv.y, di * sz + bv.z, di * sw + bv.w);
    if (relu) {
      o.x = fmaxf(o.x, 0.f);
      o.y = fmaxf(o.y, 0.f);
      o.z = fmaxf(o.z, 0.f);
      o.w = fmaxf(o.w, 0.f);
    }
    if (OUTBF)
      ((uint2*)outv)[(size_t)wid * 16 + sub] = f42bfq(o);
    else
      ((float4*)outv)[(size_t)wid * 16 + sub] = o;
  }
}

// ---------------------------------------------------------------------------
extern "C" void kernel_launch(void* const* d_in, const int* in_sizes, int n_in,
                              void* d_out, int out_size, void* d_ws, size_t ws_size,
                              hipStream_t stream) {
  const float* x = (const float*)d_in[0];
  const int* ei = (const int*)d_in[1];
  const float* W1 = (const float*)d_in[2];
  const float* b1 = (const float*)d_in[3];
  const float* W2 = (const float*)d_in[4];
  const float* b2 = (const float*)d_in[5];

  const int IN = 256;
  const int E = in_sizes[1] / 2;
  const int N = in_sizes[0] / IN;
  const int* src = ei;
  const int* dst = ei + E;
  const int nbins = (N + BIN_NODES - 1) >> BIN_SHIFT;
  const int nsup = (N + (1 << SUP_SHIFT) - 1) >> SUP_SHIFT;

  // workspace carve-up (256B aligned)
  char* ws = (char*)d_ws;
  size_t off = 0;
  auto alloc = [&](size_t bytes) -> void* {
    void* p = ws + off;
    off += (bytes + 255) & ~(size_t)255;
    return p;
  };
  int* rowptr = (int*)alloc((size_t)(N + 1) * 4);
  float* dis = (float*)alloc((size_t)N * 4);
  int* binCnt = (int*)alloc(MAX_BINS * 4);
  int* binStart = (int*)alloc((MAX_BINS + 1) * 4);
  int* supCursor = (int*)alloc(NSUP_MAX * 4);
  int* col = (int*)alloc((size_t)E * 4);            // 12.8 MB, written by bin_csr2
  uint2* out1 = (uint2*)alloc((size_t)N * 64 * 2);  // bf16 layer-1 activations
  size_t big = ((size_t)E * 4 > (size_t)N * 128) ? (size_t)E * 4 : (size_t)N * 128;
  unsigned* supbuf = (unsigned*)alloc(big);  // aliases h (supbuf dead before gemm1)
  uint2* h = (uint2*)supbuf;
  float* outf = (float*)d_out;

  const int nblkSF = (E + SF_TILE - 1) / SF_TILE;

  zero_int<<<(nbins + 255) / 256, 256, 0, stream>>>(binCnt, nbins);
  fine_count<<<512, 256, 0, stream>>>(dst, E, nbins, binCnt);
  bin_scan<<<1, 256, 0, stream>>>(binCnt, nbins, E, binStart, supCursor);
  super_fill<<<nblkSF, 256, 0, stream>>>(src, dst, E, nsup, supCursor, supbuf);
  bin_csr2<<<nbins, 256, 0, stream>>>(supbuf, binStart, nbins, N, E, rowptr, dis, col);

  gemm64<256, false><<<(N + 63) / 64, 256, 0, stream>>>(x, W1, h, N);
  agg_kernel<true><<<(N + 3) / 4, 256, 0, stream>>>(h, rowptr, col, dis, b1, out1, N, 1);
  gemm64<64, true><<<(N + 63) / 64, 256, 0, stream>>>(out1, W2, h, N);
  agg_kernel<false><<<(N + 3) / 4, 256, 0, stream>>>(h, rowptr, col, dis, b2, outf, N, 0);
}